// Round 1
// baseline (759.108 us; speedup 1.0000x reference)
//
#include <hip/hip_runtime.h>
#include <stdint.h>

typedef __attribute__((ext_vector_type(4))) float f32x4;
typedef __attribute__((ext_vector_type(8))) short s16x8;

static __device__ __forceinline__ unsigned short f2bf(float f) {
  union { float f; uint32_t u; } v; v.f = f;
  uint32_t u = v.u;
  u += 0x7fffu + ((u >> 16) & 1u);   // round-to-nearest-even bf16
  return (unsigned short)(u >> 16);
}

// ---------------- small elementwise kernels ----------------

__global__ void diag_prep(const float* __restrict__ D1, const float* __restrict__ D2,
                          const float* __restrict__ D3, const float* __restrict__ D5,
                          float* __restrict__ d1i, float* __restrict__ d2v,
                          float* __restrict__ d3v, float* __restrict__ d5p) {
  int i = blockIdx.x * blockDim.x + threadIdx.x;
  if (i < 1500) d1i[i] = 1.0f / D1[(size_t)i * 1501];
  if (i < 4000) d3v[i] = D3[(size_t)i * 4001];
  if (i < 6000) {
    d2v[i] = D2[(size_t)i * 6001];
    float v = D5[(size_t)i * 6001];
    d5p[i] = (v != 0.0f) ? 1.0f / v : 0.0f;
  }
}

__global__ void copy_chan(float* __restrict__ dst, int ldd,
                          const float* __restrict__ src,
                          const float* __restrict__ svec, int n) {
  int idx = blockIdx.x * blockDim.x + threadIdx.x;
  if (idx >= n * 32) return;
  int r = idx >> 5, f = idx & 31;
  float v = src[idx];
  if (svec) v *= svec[r];
  dst[(size_t)r * ldd + f] = v;
}

__global__ void scale_rows(float* __restrict__ dst, int ldd,
                           const float* __restrict__ svec, int n) {
  int idx = blockIdx.x * blockDim.x + threadIdx.x;
  if (idx >= n * 32) return;
  int r = idx >> 5, f = idx & 31;
  dst[(size_t)r * ldd + f] *= svec[r];
}

// seed two channels with -prev (for T2 = 2*L@T1 - prev accumulated atomically)
__global__ void seed_neg2(float* __restrict__ dA, const float* __restrict__ sA_,
                          float* __restrict__ dB, const float* __restrict__ sB_,
                          int ld, int n) {
  int idx = blockIdx.x * blockDim.x + threadIdx.x;
  if (idx >= n * 32) return;
  int r = idx >> 5, f = idx & 31;
  size_t o = (size_t)r * ld + f;
  dA[o] = -sA_[o];
  dB[o] = -sB_[o];
}

// pack one or two 32-col f32 panels (row stride lds_) into bf16 Xt[64][ldxt],
// transposed (Xt[c][r] = src[r][c]), zero-padded rows [n, ldxt)
__global__ void pack_xt2(unsigned short* __restrict__ Xt, int ldxt,
                         const float* __restrict__ src0, const float* __restrict__ src1,
                         int lds_, const float* __restrict__ svec, int n) {
  int rows = src1 ? 64 : 32;
  int total = rows * ldxt;
  int idx = blockIdx.x * blockDim.x + threadIdx.x;
  if (idx >= total) return;
  int c = idx / ldxt;
  int rr = idx - c * ldxt;
  const float* s = (c < 32) ? src0 : src1;
  int cc = c & 31;
  float v = 0.0f;
  if (rr < n) {
    v = s[(size_t)rr * lds_ + cc];
    if (svec) v *= svec[rr];
  }
  Xt[(size_t)c * ldxt + rr] = f2bf(v);
}

// Wr[k*32+i][o] = W[i][o][k]  ->  stored transposed as Xt[o][k*32+i]
__global__ void pack_w(unsigned short* __restrict__ Xt,
                       const float* __restrict__ W, int K) {
  int Kw = K * 32;
  int idx = blockIdx.x * blockDim.x + threadIdx.x;
  if (idx >= 32 * Kw) return;
  int o = idx / Kw;
  int j = idx - o * Kw;
  int k = j >> 5, i = j & 31;
  Xt[(size_t)o * Kw + j] = f2bf(W[((size_t)i * 32 + o) * K + k]);
}

// ---------------- MFMA skinny GEMM: C(+)= alpha * A(n_rows x n_k, f32) @ X(n_k x F) ----------------
// Xt is X transposed, bf16, F x ldxt, zero-padded to ldxt (multiple of 32 >= n_k).
// Block: 256 threads = 4 waves; tile 64 rows x F cols; K-step 32.
// f32 loads converted to bf16 during LDS staging; XOR-swizzled LDS to kill bank conflicts.
template <int F, bool ATOMIC, bool RELU>
__global__ __launch_bounds__(256) void mm_mfma(
    const float* __restrict__ A, int lda, int n_rows, int n_k,
    const unsigned short* __restrict__ Xt, int ldxt,
    float* __restrict__ C0, float* __restrict__ C1, int ldc,
    float alpha, int kchunk) {
  __shared__ __align__(16) unsigned short sA[64 * 32];
  __shared__ __align__(16) unsigned short sX[64 * 32];

  const int tid = threadIdx.x;
  const int k_begin = blockIdx.y * kchunk;
  const int k_end = min(n_k, k_begin + kchunk);
  if (k_begin >= k_end) return;               // uniform per block, before any barrier
  const int nsteps = (k_end - k_begin + 31) >> 5;

  const int srow = tid >> 2;                  // 0..63
  const int sslot = tid & 3;                  // 0..3 (8 elems each)
  const long arowg = (long)blockIdx.x * 64 + srow;

  f32x4 a0, a1;
  s16x8 xr = (s16x8)0;

  auto load_tiles = [&](int k0) {
    a0 = f32x4{0.f, 0.f, 0.f, 0.f};
    a1 = f32x4{0.f, 0.f, 0.f, 0.f};
    int kc = k0 + sslot * 8;
    if (arowg < n_rows) {
      const float* ap = A + (size_t)arowg * lda + kc;
      if (kc + 7 < n_k) {
        a0 = *(const f32x4*)ap;
        a1 = *(const f32x4*)(ap + 4);
      } else {
#pragma unroll
        for (int j = 0; j < 4; ++j) if (kc + j < n_k) a0[j] = ap[j];
#pragma unroll
        for (int j = 0; j < 4; ++j) if (kc + 4 + j < n_k) a1[j] = ap[4 + j];
      }
    }
    if (srow < F) xr = *(const s16x8*)(Xt + (size_t)srow * ldxt + kc);
  };

  load_tiles(k_begin);

  const int wave = tid >> 6;
  const int lane = tid & 63;
  const int g = lane >> 4;
  const int r = lane & 15;

  f32x4 acc[F / 16];
#pragma unroll
  for (int i = 0; i < F / 16; ++i) acc[i] = f32x4{0.f, 0.f, 0.f, 0.f};

  for (int s = 0; s < nsteps; ++s) {
    // stage regs -> LDS (bf16, swizzled 16B slots)
    {
      s16x8 pk;
#pragma unroll
      for (int j = 0; j < 4; ++j) pk[j] = (short)f2bf(a0[j]);
#pragma unroll
      for (int j = 0; j < 4; ++j) pk[4 + j] = (short)f2bf(a1[j]);
      int wslot = sslot ^ (srow & 3) ^ ((srow >> 2) & 3);
      *(s16x8*)&sA[srow * 32 + wslot * 8] = pk;
      if (srow < F) *(s16x8*)&sX[srow * 32 + wslot * 8] = xr;
    }
    __syncthreads();
    if (s + 1 < nsteps) load_tiles(k_begin + (s + 1) * 32);  // prefetch next tile

    int arow = wave * 16 + r;
    int aslot = g ^ (arow & 3) ^ ((arow >> 2) & 3);
    s16x8 af = *(s16x8*)&sA[arow * 32 + aslot * 8];
#pragma unroll
    for (int nt = 0; nt < F / 16; ++nt) {
      int xc = nt * 16 + r;
      int xslot = g ^ (xc & 3) ^ ((xc >> 2) & 3);
      s16x8 bfr = *(s16x8*)&sX[xc * 32 + xslot * 8];
      acc[nt] = __builtin_amdgcn_mfma_f32_16x16x32_bf16(af, bfr, acc[nt], 0, 0, 0);
    }
    __syncthreads();
  }

  // epilogue: C/D layout col = lane&15, row = (lane>>4)*4 + reg
#pragma unroll
  for (int nt = 0; nt < F / 16; ++nt) {
    float* C = (F == 64 && nt >= 2) ? C1 : C0;
    int col = ((F == 64) ? (nt & 1) : nt) * 16 + r;
#pragma unroll
    for (int j = 0; j < 4; ++j) {
      long row = (long)blockIdx.x * 64 + wave * 16 + g * 4 + j;
      if (row < n_rows) {
        float v = alpha * acc[nt][j];
        if (ATOMIC) {
          atomicAdd(&C[(size_t)row * ldc + col], v);
        } else {
          if (RELU) v = fmaxf(v, 0.0f);
          C[(size_t)row * ldc + col] = v;
        }
      }
    }
  }
}

// ---------------- fp32 transposed GEMM: C(n x 32) (+)= A^T @ X, A: m x lda (cols [0,n)), X: m x 32 ----------------
__global__ __launch_bounds__(256) void mm_at(
    const float* __restrict__ A, int lda, int m,
    const float* __restrict__ X,
    float* __restrict__ C, int ldc, int n, int kchunk) {
  const int fg = threadIdx.x & 3;
  const int cg = threadIdx.x >> 2;
  const int c = blockIdx.x * 256 + cg * 4;
  const int k0 = blockIdx.y * kchunk;
  const int k1 = min(m, k0 + kchunk);
  const int f = fg * 8;
  float acc[4][8];
#pragma unroll
  for (int a = 0; a < 4; ++a)
#pragma unroll
    for (int b = 0; b < 8; ++b) acc[a][b] = 0.f;

  for (int k = k0; k < k1; ++k) {
    const float* Ar = A + (size_t)k * lda + c;
    f32x4 a;
    if (c + 3 < n) {
      a = *(const f32x4*)Ar;
    } else {
      a = f32x4{0.f, 0.f, 0.f, 0.f};
#pragma unroll
      for (int j = 0; j < 4; ++j) if (c + j < n) a[j] = Ar[j];
    }
    f32x4 xa = *(const f32x4*)(X + (size_t)k * 32 + f);
    f32x4 xb = *(const f32x4*)(X + (size_t)k * 32 + f + 4);
#pragma unroll
    for (int cc = 0; cc < 4; ++cc) {
#pragma unroll
      for (int jj = 0; jj < 4; ++jj) {
        acc[cc][jj] += a[cc] * xa[jj];
        acc[cc][4 + jj] += a[cc] * xb[jj];
      }
    }
  }
  if (c >= n) return;
#pragma unroll
  for (int cc = 0; cc < 4; ++cc) {
    if (c + cc >= n) break;
#pragma unroll
    for (int jj = 0; jj < 8; ++jj)
      atomicAdd(&C[(size_t)(c + cc) * ldc + f + jj], acc[cc][jj]);
  }
}

// ---------------- host ----------------

extern "C" void kernel_launch(void* const* d_in, const int* in_sizes, int n_in,
                              void* d_out, int out_size, void* d_ws, size_t ws_size,
                              hipStream_t stream) {
  (void)in_sizes; (void)n_in; (void)out_size; (void)ws_size;
  const float* x0  = (const float*)d_in[0];
  const float* x1  = (const float*)d_in[1];
  const float* x2  = (const float*)d_in[2];
  const float* B1  = (const float*)d_in[3];
  const float* B2  = (const float*)d_in[4];
  const float* L0  = (const float*)d_in[5];
  const float* L1l = (const float*)d_in[6];
  const float* L1u = (const float*)d_in[7];
  const float* L2  = (const float*)d_in[8];
  const float* D1  = (const float*)d_in[9];
  const float* D2  = (const float*)d_in[10];
  const float* D3  = (const float*)d_in[11];
  const float* D5  = (const float*)d_in[12];
  const float* W0  = (const float*)d_in[13];
  const float* W1  = (const float*)d_in[14];
  const float* W2  = (const float*)d_in[15];
  float* out = (float*)d_out;

  char* p = (char*)d_ws;
  auto alloc = [&](size_t b) { char* r = p; p += (b + 255) & ~(size_t)255; return r; };
  float* d1i = (float*)alloc(1500 * 4);
  float* d2v = (float*)alloc(6000 * 4);
  float* d3v = (float*)alloc(4000 * 4);
  float* d5p = (float*)alloc(6000 * 4);
  float* z0  = (float*)alloc((size_t)1500 * 32 * 4);
  float* sx1 = (float*)alloc((size_t)6000 * 32 * 4);
  float* X0a = (float*)alloc((size_t)1500 * 192 * 4);   // 6 channels x 32
  float* X1a = (float*)alloc((size_t)6000 * 352 * 4);   // 11 channels x 32
  float* X2a = (float*)alloc((size_t)4000 * 192 * 4);   // 6 channels x 32
  unsigned short* Xt = (unsigned short*)alloc((size_t)64 * 6144 * 2);

  auto nb = [](int total) { return (unsigned)((total + 255) / 256); };

  hipMemsetAsync(X0a, 0, (size_t)1500 * 192 * 4, stream);
  hipMemsetAsync(X1a, 0, (size_t)6000 * 352 * 4, stream);
  hipMemsetAsync(X2a, 0, (size_t)4000 * 192 * 4, stream);

  diag_prep<<<24, 256, 0, stream>>>(D1, D2, D3, D5, d1i, d2v, d3v, d5p);

  // identity channels + prescaled operands
  copy_chan<<<nb(1500 * 32), 256, 0, stream>>>(X0a + 0 * 32, 192, x0, nullptr, 1500);
  copy_chan<<<nb(6000 * 32), 256, 0, stream>>>(X1a + 3 * 32, 352, x1, nullptr, 6000);
  copy_chan<<<nb(4000 * 32), 256, 0, stream>>>(X2a + 3 * 32, 192, x2, nullptr, 4000);
  copy_chan<<<nb(1500 * 32), 256, 0, stream>>>(z0, 32, x0, d1i, 1500);     // inv(D1) x0
  copy_chan<<<nb(6000 * 32), 256, 0, stream>>>(sx1, 32, x1, d5p, 6000);    // pinv(D5) x1

  // x0p = d1i * (B1 @ x1)  -> X0 ch3
  pack_xt2<<<nb(32 * 6016), 256, 0, stream>>>(Xt, 6016, x1, nullptr, 32, nullptr, 6000);
  mm_mfma<32, true, false><<<dim3(24, 24), 256, 0, stream>>>(B1, 6000, 1500, 6000, Xt, 6016,
                                                             X0a + 3 * 32, nullptr, 192, 1.f, 256);
  scale_rows<<<nb(1500 * 32), 256, 0, stream>>>(X0a + 3 * 32, 192, d1i, 1500);

  // x1n = d2 * (B1^T @ z0) -> X1 ch0
  mm_at<<<dim3(24, 24), 256, 0, stream>>>(B1, 6000, 1500, z0, X1a + 0 * 32, 352, 6000, 63);
  scale_rows<<<nb(6000 * 32), 256, 0, stream>>>(X1a + 0 * 32, 352, d2v, 6000);

  // x1p = B2 @ (d3 * x2) -> X1 ch8
  pack_xt2<<<nb(32 * 4000), 256, 0, stream>>>(Xt, 4000, x2, nullptr, 32, d3v, 4000);
  mm_mfma<32, true, false><<<dim3(94, 8), 256, 0, stream>>>(B2, 4000, 6000, 4000, Xt, 4000,
                                                            X1a + 8 * 32, nullptr, 352, 1.f, 512);

  // x2n = B2^T @ sx1 -> X2 ch0
  mm_at<<<dim3(16, 32), 256, 0, stream>>>(B2, 4000, 6000, sx1, X2a + 0 * 32, 192, 4000, 188);

  // ---- cheb L0 on [c0, c3] ----
  pack_xt2<<<nb(64 * 1504), 256, 0, stream>>>(Xt, 1504, X0a + 0 * 32, X0a + 3 * 32, 192, nullptr, 1500);
  mm_mfma<64, true, false><<<dim3(24, 24), 256, 0, stream>>>(L0, 1500, 1500, 1500, Xt, 1504,
                                                             X0a + 1 * 32, X0a + 4 * 32, 192, 1.f, 64);
  pack_xt2<<<nb(64 * 1504), 256, 0, stream>>>(Xt, 1504, X0a + 1 * 32, X0a + 4 * 32, 192, nullptr, 1500);
  seed_neg2<<<nb(1500 * 32), 256, 0, stream>>>(X0a + 2 * 32, X0a + 0 * 32, X0a + 5 * 32, X0a + 3 * 32, 192, 1500);
  mm_mfma<64, true, false><<<dim3(24, 24), 256, 0, stream>>>(L0, 1500, 1500, 1500, Xt, 1504,
                                                             X0a + 2 * 32, X0a + 5 * 32, 192, 2.f, 64);

  // ---- cheb L1l on [c0, c3] ----
  pack_xt2<<<nb(64 * 6016), 256, 0, stream>>>(Xt, 6016, X1a + 0 * 32, X1a + 3 * 32, 352, nullptr, 6000);
  mm_mfma<64, true, false><<<dim3(94, 8), 256, 0, stream>>>(L1l, 6000, 6000, 6000, Xt, 6016,
                                                            X1a + 1 * 32, X1a + 4 * 32, 352, 1.f, 768);
  pack_xt2<<<nb(64 * 6016), 256, 0, stream>>>(Xt, 6016, X1a + 1 * 32, X1a + 4 * 32, 352, nullptr, 6000);
  seed_neg2<<<nb(6000 * 32), 256, 0, stream>>>(X1a + 2 * 32, X1a + 0 * 32, X1a + 5 * 32, X1a + 3 * 32, 352, 6000);
  mm_mfma<64, true, false><<<dim3(94, 8), 256, 0, stream>>>(L1l, 6000, 6000, 6000, Xt, 6016,
                                                            X1a + 2 * 32, X1a + 5 * 32, 352, 2.f, 768);

  // ---- cheb L1u on [c3, c8] ----
  pack_xt2<<<nb(64 * 6016), 256, 0, stream>>>(Xt, 6016, X1a + 3 * 32, X1a + 8 * 32, 352, nullptr, 6000);
  mm_mfma<64, true, false><<<dim3(94, 8), 256, 0, stream>>>(L1u, 6000, 6000, 6000, Xt, 6016,
                                                            X1a + 6 * 32, X1a + 9 * 32, 352, 1.f, 768);
  pack_xt2<<<nb(64 * 6016), 256, 0, stream>>>(Xt, 6016, X1a + 6 * 32, X1a + 9 * 32, 352, nullptr, 6000);
  seed_neg2<<<nb(6000 * 32), 256, 0, stream>>>(X1a + 7 * 32, X1a + 3 * 32, X1a + 10 * 32, X1a + 8 * 32, 352, 6000);
  mm_mfma<64, true, false><<<dim3(94, 8), 256, 0, stream>>>(L1u, 6000, 6000, 6000, Xt, 6016,
                                                            X1a + 7 * 32, X1a + 10 * 32, 352, 2.f, 768);

  // ---- cheb L2 on [c0, c3] ----
  pack_xt2<<<nb(64 * 4000), 256, 0, stream>>>(Xt, 4000, X2a + 0 * 32, X2a + 3 * 32, 192, nullptr, 4000);
  mm_mfma<64, true, false><<<dim3(63, 12), 256, 0, stream>>>(L2, 4000, 4000, 4000, Xt, 4000,
                                                             X2a + 1 * 32, X2a + 4 * 32, 192, 1.f, 352);
  pack_xt2<<<nb(64 * 4000), 256, 0, stream>>>(Xt, 4000, X2a + 1 * 32, X2a + 4 * 32, 192, nullptr, 4000);
  seed_neg2<<<nb(4000 * 32), 256, 0, stream>>>(X2a + 2 * 32, X2a + 0 * 32, X2a + 5 * 32, X2a + 3 * 32, 192, 4000);
  mm_mfma<64, true, false><<<dim3(63, 12), 256, 0, stream>>>(L2, 4000, 4000, 4000, Xt, 4000,
                                                             X2a + 2 * 32, X2a + 5 * 32, 192, 2.f, 352);

  // ---- combine: y = relu(Xall @ Wr), direct store to d_out ----
  pack_w<<<nb(32 * 192), 256, 0, stream>>>(Xt, W0, 6);
  mm_mfma<32, false, true><<<dim3(24, 1), 256, 0, stream>>>(X0a, 192, 1500, 192, Xt, 192,
                                                            out, nullptr, 32, 1.f, 192);
  pack_w<<<nb(32 * 352), 256, 0, stream>>>(Xt, W1, 11);
  mm_mfma<32, false, true><<<dim3(94, 1), 256, 0, stream>>>(X1a, 352, 6000, 352, Xt, 352,
                                                            out + 48000, nullptr, 32, 1.f, 352);
  pack_w<<<nb(32 * 192), 256, 0, stream>>>(Xt, W2, 6);
  mm_mfma<32, false, true><<<dim3(63, 1), 256, 0, stream>>>(X2a, 192, 4000, 192, Xt, 192,
                                                            out + 240000, nullptr, 32, 1.f, 192);
}

// Round 2
// 439.816 us; speedup vs baseline: 1.7260x; 1.7260x over previous
//
#include <hip/hip_runtime.h>
#include <stdint.h>

typedef __attribute__((ext_vector_type(4))) float f32x4;
typedef __attribute__((ext_vector_type(8))) short s16x8;

static __device__ __forceinline__ unsigned short f2bf(float f) {
  union { float f; uint32_t u; } v; v.f = f;
  uint32_t u = v.u;
  u += 0x7fffu + ((u >> 16) & 1u);   // round-to-nearest-even bf16
  return (unsigned short)(u >> 16);
}

// ---------------- small elementwise kernels ----------------

__global__ void diag_prep(const float* __restrict__ D1, const float* __restrict__ D2,
                          const float* __restrict__ D3, const float* __restrict__ D5,
                          float* __restrict__ d1i, float* __restrict__ d2v,
                          float* __restrict__ d3v, float* __restrict__ d5p) {
  int i = blockIdx.x * blockDim.x + threadIdx.x;
  if (i < 1500) d1i[i] = 1.0f / D1[(size_t)i * 1501];
  if (i < 4000) d3v[i] = D3[(size_t)i * 4001];
  if (i < 6000) {
    d2v[i] = D2[(size_t)i * 6001];
    float v = D5[(size_t)i * 6001];
    d5p[i] = (v != 0.0f) ? 1.0f / v : 0.0f;
  }
}

__global__ void copy_chan(float* __restrict__ dst, int ldd,
                          const float* __restrict__ src,
                          const float* __restrict__ svec, int n) {
  int idx = blockIdx.x * blockDim.x + threadIdx.x;
  if (idx >= n * 32) return;
  int r = idx >> 5, f = idx & 31;
  float v = src[idx];
  if (svec) v *= svec[r];
  dst[(size_t)r * ldd + f] = v;
}

__global__ void scale_rows(float* __restrict__ dst, int ldd,
                           const float* __restrict__ svec, int n) {
  int idx = blockIdx.x * blockDim.x + threadIdx.x;
  if (idx >= n * 32) return;
  int r = idx >> 5, f = idx & 31;
  dst[(size_t)r * ldd + f] *= svec[r];
}

// seed two channels with -prev (for T2 = 2*L@T1 - prev accumulated atomically)
__global__ void seed_neg2(float* __restrict__ dA, const float* __restrict__ sA_,
                          float* __restrict__ dB, const float* __restrict__ sB_,
                          int ld, int n) {
  int idx = blockIdx.x * blockDim.x + threadIdx.x;
  if (idx >= n * 32) return;
  int r = idx >> 5, f = idx & 31;
  size_t o = (size_t)r * ld + f;
  dA[o] = -sA_[o];
  dB[o] = -sB_[o];
}

// ---------------- LDS-tiled pack: Xt[64][ldxt] = [src0|src1]^T (bf16), optional row scaling ----------------
// src0/src1: 32-col f32 panels with row stride lds_. Xt row c<32 from src0, c>=32 from src1 (zeros if null).
// Zero-pads cols [n, ldxt). grid.x = ceil(ldxt/64).
__global__ __launch_bounds__(256) void pack_panels(
    unsigned short* __restrict__ Xt, int ldxt,
    const float* __restrict__ src0, const float* __restrict__ src1,
    int lds_, const float* __restrict__ svec, int n) {
  __shared__ unsigned short sT[64][76];
  const int t = threadIdx.x;
  const int tr0 = blockIdx.x * 64;     // src-row tile (out-col tile)
  const int c0 = (t & 15) * 4;         // combined col 0..63
  const int r0 = (t >> 4) * 4;
  const float* s = (c0 < 32) ? src0 : src1;
  const int cc = c0 & 31;
  float vv[4][4];
#pragma unroll
  for (int j = 0; j < 4; ++j) {
    int gr = tr0 + r0 + j;
    f32x4 v = {0.f, 0.f, 0.f, 0.f};
    if (s && gr < n) {
      v = *(const f32x4*)(s + (size_t)gr * lds_ + cc);
      if (svec) {
        float sc = svec[gr];
#pragma unroll
        for (int jj = 0; jj < 4; ++jj) v[jj] *= sc;
      }
    }
#pragma unroll
    for (int jj = 0; jj < 4; ++jj) vv[j][jj] = v[jj];
  }
#pragma unroll
  for (int jj = 0; jj < 4; ++jj) {
    union { unsigned short u[4]; unsigned long long ll; } w;
#pragma unroll
    for (int j = 0; j < 4; ++j) w.u[j] = f2bf(vv[j][jj]);
    *(unsigned long long*)&sT[c0 + jj][r0] = w.ll;
  }
  __syncthreads();
#pragma unroll
  for (int p = 0; p < 2; ++p) {
    int orow = (t >> 3) + p * 32;
    int rcol = (t & 7) * 8;
    int gcol = tr0 + rcol;
    if (gcol < ldxt) {
      union { unsigned long long ll[2]; s16x8 v; } w;
      w.ll[0] = *(const unsigned long long*)&sT[orow][rcol];
      w.ll[1] = *(const unsigned long long*)&sT[orow][rcol + 4];
      *(s16x8*)(Xt + (size_t)orow * ldxt + gcol) = w.v;
    }
  }
}

// ---------------- big transpose + f32->bf16: out(nO x ldo) = in^T, in: nI x ldi (real cols = nO) ----------------
// Zero-pads out cols [nI, ldo). grid = (ceil(nO/64), ceil(ldo/64)).
__global__ __launch_bounds__(256) void transpose_big(
    const float* __restrict__ in, int ldi, int nI,
    unsigned short* __restrict__ outp, int ldo, int nO) {
  __shared__ unsigned short sT[64][76];
  const int t = threadIdx.x;
  const int tc0 = blockIdx.x * 64;   // in-col tile = out-row tile
  const int tr0 = blockIdx.y * 64;   // in-row tile = out-col tile
  const int c0 = (t & 15) * 4;
  const int r0 = (t >> 4) * 4;
  float vv[4][4];
#pragma unroll
  for (int j = 0; j < 4; ++j) {
    int gr = tr0 + r0 + j;
    f32x4 v = {0.f, 0.f, 0.f, 0.f};
    if (gr < nI) {
      const float* pI = in + (size_t)gr * ldi + tc0 + c0;
      if (tc0 + c0 + 3 < nO) {
        v = *(const f32x4*)pI;
      } else {
#pragma unroll
        for (int jj = 0; jj < 4; ++jj) if (tc0 + c0 + jj < nO) v[jj] = pI[jj];
      }
    }
#pragma unroll
    for (int jj = 0; jj < 4; ++jj) vv[j][jj] = v[jj];
  }
#pragma unroll
  for (int jj = 0; jj < 4; ++jj) {
    union { unsigned short u[4]; unsigned long long ll; } w;
#pragma unroll
    for (int j = 0; j < 4; ++j) w.u[j] = f2bf(vv[j][jj]);
    *(unsigned long long*)&sT[c0 + jj][r0] = w.ll;
  }
  __syncthreads();
#pragma unroll
  for (int p = 0; p < 2; ++p) {
    int orow = (t >> 3) + p * 32;
    int rcol = (t & 7) * 8;
    int grow = tc0 + orow;
    int gcol = tr0 + rcol;
    if (grow < nO && gcol < ldo) {
      union { unsigned long long ll[2]; s16x8 v; } w;
      w.ll[0] = *(const unsigned long long*)&sT[orow][rcol];
      w.ll[1] = *(const unsigned long long*)&sT[orow][rcol + 4];
      *(s16x8*)(outp + (size_t)grow * ldo + gcol) = w.v;
    }
  }
}

// Wr[k*32+i][o] = W[i][o][k]  ->  stored transposed as Xt[o][k*32+i]
__global__ void pack_w(unsigned short* __restrict__ Xt,
                       const float* __restrict__ W, int K) {
  int Kw = K * 32;
  int idx = blockIdx.x * blockDim.x + threadIdx.x;
  if (idx >= 32 * Kw) return;
  int o = idx / Kw;
  int j = idx - o * Kw;
  int k = j >> 5, i = j & 31;
  Xt[(size_t)o * Kw + j] = f2bf(W[((size_t)i * 32 + o) * K + k]);
}

// ---------------- MFMA skinny GEMM: C(+)= alpha * A(n_rows x n_k) @ X(n_k x F) ----------------
// A: f32 or bf16 row-major. Xt is X transposed, bf16, F x ldxt, zero-padded.
template <int F, bool ATOMIC, bool RELU, typename AT>
__global__ __launch_bounds__(256) void mm_mfma(
    const AT* __restrict__ A, int lda, int n_rows, int n_k,
    const unsigned short* __restrict__ Xt, int ldxt,
    float* __restrict__ C0, float* __restrict__ C1, int ldc,
    float alpha, int kchunk) {
  __shared__ __align__(16) unsigned short sA[64 * 32];
  __shared__ __align__(16) unsigned short sX[64 * 32];

  const int tid = threadIdx.x;
  const int k_begin = blockIdx.y * kchunk;
  const int k_end = min(n_k, k_begin + kchunk);
  if (k_begin >= k_end) return;               // uniform per block, before any barrier
  const int nsteps = (k_end - k_begin + 31) >> 5;

  const int srow = tid >> 2;                  // 0..63
  const int sslot = tid & 3;                  // 0..3 (8 elems each)
  const long arowg = (long)blockIdx.x * 64 + srow;

  f32x4 a0, a1;
  s16x8 abf = (s16x8)0;
  s16x8 xr = (s16x8)0;

  auto load_tiles = [&](int k0) {
    int kc = k0 + sslot * 8;
    if constexpr (sizeof(AT) == 4) {
      a0 = f32x4{0.f, 0.f, 0.f, 0.f};
      a1 = f32x4{0.f, 0.f, 0.f, 0.f};
      if (arowg < n_rows) {
        const float* ap = (const float*)A + (size_t)arowg * lda + kc;
        if (kc + 7 < n_k) {
          a0 = *(const f32x4*)ap;
          a1 = *(const f32x4*)(ap + 4);
        } else {
#pragma unroll
          for (int j = 0; j < 4; ++j) if (kc + j < n_k) a0[j] = ap[j];
#pragma unroll
          for (int j = 0; j < 4; ++j) if (kc + 4 + j < n_k) a1[j] = ap[4 + j];
        }
      }
    } else {
      abf = (s16x8)0;
      if (arowg < n_rows) {
        const unsigned short* ap = (const unsigned short*)A + (size_t)arowg * lda + kc;
        if (kc + 7 < n_k) {
          abf = *(const s16x8*)ap;
        } else {
#pragma unroll
          for (int j = 0; j < 8; ++j) if (kc + j < n_k) abf[j] = (short)ap[j];
        }
      }
    }
    if (srow < F) xr = *(const s16x8*)(Xt + (size_t)srow * ldxt + kc);
  };

  load_tiles(k_begin);

  const int wave = tid >> 6;
  const int lane = tid & 63;
  const int g = lane >> 4;
  const int r = lane & 15;

  f32x4 acc[F / 16];
#pragma unroll
  for (int i = 0; i < F / 16; ++i) acc[i] = f32x4{0.f, 0.f, 0.f, 0.f};

  for (int s = 0; s < nsteps; ++s) {
    // stage regs -> LDS (bf16, swizzled 16B slots)
    {
      s16x8 pk;
      if constexpr (sizeof(AT) == 4) {
#pragma unroll
        for (int j = 0; j < 4; ++j) pk[j] = (short)f2bf(a0[j]);
#pragma unroll
        for (int j = 0; j < 4; ++j) pk[4 + j] = (short)f2bf(a1[j]);
      } else {
        pk = abf;
      }
      int wslot = sslot ^ (srow & 3) ^ ((srow >> 2) & 3);
      *(s16x8*)&sA[srow * 32 + wslot * 8] = pk;
      if (srow < F) *(s16x8*)&sX[srow * 32 + wslot * 8] = xr;
    }
    __syncthreads();
    if (s + 1 < nsteps) load_tiles(k_begin + (s + 1) * 32);  // prefetch next tile

    int arow = wave * 16 + r;
    int aslot = g ^ (arow & 3) ^ ((arow >> 2) & 3);
    s16x8 af = *(s16x8*)&sA[arow * 32 + aslot * 8];
#pragma unroll
    for (int nt = 0; nt < F / 16; ++nt) {
      int xc = nt * 16 + r;
      int xslot = g ^ (xc & 3) ^ ((xc >> 2) & 3);
      s16x8 bfr = *(s16x8*)&sX[xc * 32 + xslot * 8];
      acc[nt] = __builtin_amdgcn_mfma_f32_16x16x32_bf16(af, bfr, acc[nt], 0, 0, 0);
    }
    __syncthreads();
  }

  // epilogue: C/D layout col = lane&15, row = (lane>>4)*4 + reg
#pragma unroll
  for (int nt = 0; nt < F / 16; ++nt) {
    float* C = (F == 64 && nt >= 2) ? C1 : C0;
    int col = ((F == 64) ? (nt & 1) : nt) * 16 + r;
#pragma unroll
    for (int j = 0; j < 4; ++j) {
      long row = (long)blockIdx.x * 64 + wave * 16 + g * 4 + j;
      if (row < n_rows) {
        float v = alpha * acc[nt][j];
        if (ATOMIC) {
          atomicAdd(&C[(size_t)row * ldc + col], v);
        } else {
          if (RELU) v = fmaxf(v, 0.0f);
          C[(size_t)row * ldc + col] = v;
        }
      }
    }
  }
}

// ---------------- fp32 transposed GEMM (fallback only if ws too small) ----------------
__global__ __launch_bounds__(256) void mm_at(
    const float* __restrict__ A, int lda, int m,
    const float* __restrict__ X,
    float* __restrict__ C, int ldc, int n, int kchunk) {
  const int fg = threadIdx.x & 3;
  const int cg = threadIdx.x >> 2;
  const int c = blockIdx.x * 256 + cg * 4;
  const int k0 = blockIdx.y * kchunk;
  const int k1 = min(m, k0 + kchunk);
  const int f = fg * 8;
  float acc[4][8];
#pragma unroll
  for (int a = 0; a < 4; ++a)
#pragma unroll
    for (int b = 0; b < 8; ++b) acc[a][b] = 0.f;

  for (int k = k0; k < k1; ++k) {
    const float* Ar = A + (size_t)k * lda + c;
    f32x4 a;
    if (c + 3 < n) {
      a = *(const f32x4*)Ar;
    } else {
      a = f32x4{0.f, 0.f, 0.f, 0.f};
#pragma unroll
      for (int j = 0; j < 4; ++j) if (c + j < n) a[j] = Ar[j];
    }
    f32x4 xa = *(const f32x4*)(X + (size_t)k * 32 + f);
    f32x4 xb = *(const f32x4*)(X + (size_t)k * 32 + f + 4);
#pragma unroll
    for (int cc = 0; cc < 4; ++cc) {
#pragma unroll
      for (int jj = 0; jj < 4; ++jj) {
        acc[cc][jj] += a[cc] * xa[jj];
        acc[cc][4 + jj] += a[cc] * xb[jj];
      }
    }
  }
  if (c >= n) return;
#pragma unroll
  for (int cc = 0; cc < 4; ++cc) {
    if (c + cc >= n) break;
#pragma unroll
    for (int jj = 0; jj < 8; ++jj)
      atomicAdd(&C[(size_t)(c + cc) * ldc + f + jj], acc[cc][jj]);
  }
}

// ---------------- host ----------------

extern "C" void kernel_launch(void* const* d_in, const int* in_sizes, int n_in,
                              void* d_out, int out_size, void* d_ws, size_t ws_size,
                              hipStream_t stream) {
  (void)in_sizes; (void)n_in; (void)out_size;
  const float* x0  = (const float*)d_in[0];
  const float* x1  = (const float*)d_in[1];
  const float* x2  = (const float*)d_in[2];
  const float* B1  = (const float*)d_in[3];
  const float* B2  = (const float*)d_in[4];
  const float* L0  = (const float*)d_in[5];
  const float* L1l = (const float*)d_in[6];
  const float* L1u = (const float*)d_in[7];
  const float* L2  = (const float*)d_in[8];
  const float* D1  = (const float*)d_in[9];
  const float* D2  = (const float*)d_in[10];
  const float* D3  = (const float*)d_in[11];
  const float* D5  = (const float*)d_in[12];
  const float* W0  = (const float*)d_in[13];
  const float* W1  = (const float*)d_in[14];
  const float* W2  = (const float*)d_in[15];
  float* out = (float*)d_out;

  char* p = (char*)d_ws;
  auto alloc = [&](size_t b) { char* r = p; p += (b + 255) & ~(size_t)255; return r; };
  float* d1i = (float*)alloc(1500 * 4);
  float* d2v = (float*)alloc(6000 * 4);
  float* d3v = (float*)alloc(4000 * 4);
  float* d5p = (float*)alloc(6000 * 4);
  float* X0a = (float*)alloc((size_t)1500 * 192 * 4);   // 6 channels x 32
  float* X1a = (float*)alloc((size_t)6000 * 352 * 4);   // 11 channels x 32
  float* X2a = (float*)alloc((size_t)4000 * 192 * 4);   // 6 channels x 32
  unsigned short* Xt = (unsigned short*)alloc((size_t)64 * 6144 * 2);

  size_t used_common = (size_t)(p - (char*)d_ws);
  bool fast_t = (used_common + (size_t)6000 * 1504 * 2 + (size_t)4000 * 6016 * 2 + 4096) <= ws_size;
  unsigned short* B1t = nullptr;
  unsigned short* B2t = nullptr;
  float* z0 = nullptr;
  float* sx1 = nullptr;
  if (fast_t) {
    B1t = (unsigned short*)alloc((size_t)6000 * 1504 * 2);
    B2t = (unsigned short*)alloc((size_t)4000 * 6016 * 2);
  } else {
    z0  = (float*)alloc((size_t)1500 * 32 * 4);
    sx1 = (float*)alloc((size_t)6000 * 32 * 4);
  }

  auto nb = [](int total) { return (unsigned)((total + 255) / 256); };

  hipMemsetAsync(X0a, 0, (size_t)1500 * 192 * 4, stream);
  hipMemsetAsync(X1a, 0, (size_t)6000 * 352 * 4, stream);
  hipMemsetAsync(X2a, 0, (size_t)4000 * 192 * 4, stream);

  diag_prep<<<24, 256, 0, stream>>>(D1, D2, D3, D5, d1i, d2v, d3v, d5p);

  // identity channels
  copy_chan<<<nb(1500 * 32), 256, 0, stream>>>(X0a + 0 * 32, 192, x0, nullptr, 1500);
  copy_chan<<<nb(6000 * 32), 256, 0, stream>>>(X1a + 3 * 32, 352, x1, nullptr, 6000);
  copy_chan<<<nb(4000 * 32), 256, 0, stream>>>(X2a + 3 * 32, 192, x2, nullptr, 4000);

  if (fast_t) {
    transpose_big<<<dim3(94, 24), 256, 0, stream>>>(B1, 6000, 1500, B1t, 1504, 6000);
    transpose_big<<<dim3(63, 94), 256, 0, stream>>>(B2, 4000, 6000, B2t, 6016, 4000);
  } else {
    copy_chan<<<nb(1500 * 32), 256, 0, stream>>>(z0, 32, x0, d1i, 1500);
    copy_chan<<<nb(6000 * 32), 256, 0, stream>>>(sx1, 32, x1, d5p, 6000);
  }

  // x0p = d1i * (B1 @ x1)  -> X0 ch3
  pack_panels<<<94, 256, 0, stream>>>(Xt, 6016, x1, nullptr, 32, nullptr, 6000);
  mm_mfma<32, true, false><<<dim3(24, 24), 256, 0, stream>>>(B1, 6000, 1500, 6000, Xt, 6016,
                                                             X0a + 3 * 32, nullptr, 192, 1.f, 256);
  scale_rows<<<nb(1500 * 32), 256, 0, stream>>>(X0a + 3 * 32, 192, d1i, 1500);

  // x1n = d2 * (B1^T @ (d1i*x0)) -> X1 ch0
  if (fast_t) {
    pack_panels<<<24, 256, 0, stream>>>(Xt, 1504, x0, nullptr, 32, d1i, 1500);
    mm_mfma<32, true, false><<<dim3(94, 6), 256, 0, stream>>>(B1t, 1504, 6000, 1504, Xt, 1504,
                                                              X1a + 0 * 32, nullptr, 352, 1.f, 256);
  } else {
    mm_at<<<dim3(24, 24), 256, 0, stream>>>(B1, 6000, 1500, z0, X1a + 0 * 32, 352, 6000, 63);
  }
  scale_rows<<<nb(6000 * 32), 256, 0, stream>>>(X1a + 0 * 32, 352, d2v, 6000);

  // x1p = B2 @ (d3 * x2) -> X1 ch8
  pack_panels<<<63, 256, 0, stream>>>(Xt, 4000, x2, nullptr, 32, d3v, 4000);
  mm_mfma<32, true, false><<<dim3(94, 8), 256, 0, stream>>>(B2, 4000, 6000, 4000, Xt, 4000,
                                                            X1a + 8 * 32, nullptr, 352, 1.f, 512);

  // x2n = B2^T @ (d5p * x1) -> X2 ch0
  if (fast_t) {
    pack_panels<<<94, 256, 0, stream>>>(Xt, 6016, x1, nullptr, 32, d5p, 6000);
    mm_mfma<32, true, false><<<dim3(63, 8), 256, 0, stream>>>(B2t, 6016, 4000, 6016, Xt, 6016,
                                                              X2a + 0 * 32, nullptr, 192, 1.f, 768);
  } else {
    mm_at<<<dim3(16, 32), 256, 0, stream>>>(B2, 4000, 6000, sx1, X2a + 0 * 32, 192, 4000, 188);
  }

  // ---- cheb L0 on [c0, c3] ----
  pack_panels<<<24, 256, 0, stream>>>(Xt, 1504, X0a + 0 * 32, X0a + 3 * 32, 192, nullptr, 1500);
  mm_mfma<64, true, false><<<dim3(24, 24), 256, 0, stream>>>(L0, 1500, 1500, 1500, Xt, 1504,
                                                             X0a + 1 * 32, X0a + 4 * 32, 192, 1.f, 64);
  pack_panels<<<24, 256, 0, stream>>>(Xt, 1504, X0a + 1 * 32, X0a + 4 * 32, 192, nullptr, 1500);
  seed_neg2<<<nb(1500 * 32), 256, 0, stream>>>(X0a + 2 * 32, X0a + 0 * 32, X0a + 5 * 32, X0a + 3 * 32, 192, 1500);
  mm_mfma<64, true, false><<<dim3(24, 24), 256, 0, stream>>>(L0, 1500, 1500, 1500, Xt, 1504,
                                                             X0a + 2 * 32, X0a + 5 * 32, 192, 2.f, 64);

  // ---- cheb L1l on [c0, c3] ----
  pack_panels<<<94, 256, 0, stream>>>(Xt, 6016, X1a + 0 * 32, X1a + 3 * 32, 352, nullptr, 6000);
  mm_mfma<64, true, false><<<dim3(94, 8), 256, 0, stream>>>(L1l, 6000, 6000, 6000, Xt, 6016,
                                                            X1a + 1 * 32, X1a + 4 * 32, 352, 1.f, 768);
  pack_panels<<<94, 256, 0, stream>>>(Xt, 6016, X1a + 1 * 32, X1a + 4 * 32, 352, nullptr, 6000);
  seed_neg2<<<nb(6000 * 32), 256, 0, stream>>>(X1a + 2 * 32, X1a + 0 * 32, X1a + 5 * 32, X1a + 3 * 32, 352, 6000);
  mm_mfma<64, true, false><<<dim3(94, 8), 256, 0, stream>>>(L1l, 6000, 6000, 6000, Xt, 6016,
                                                            X1a + 2 * 32, X1a + 5 * 32, 352, 2.f, 768);

  // ---- cheb L1u on [c3, c8] ----
  pack_panels<<<94, 256, 0, stream>>>(Xt, 6016, X1a + 3 * 32, X1a + 8 * 32, 352, nullptr, 6000);
  mm_mfma<64, true, false><<<dim3(94, 8), 256, 0, stream>>>(L1u, 6000, 6000, 6000, Xt, 6016,
                                                            X1a + 6 * 32, X1a + 9 * 32, 352, 1.f, 768);
  pack_panels<<<94, 256, 0, stream>>>(Xt, 6016, X1a + 6 * 32, X1a + 9 * 32, 352, nullptr, 6000);
  seed_neg2<<<nb(6000 * 32), 256, 0, stream>>>(X1a + 7 * 32, X1a + 3 * 32, X1a + 10 * 32, X1a + 8 * 32, 352, 6000);
  mm_mfma<64, true, false><<<dim3(94, 8), 256, 0, stream>>>(L1u, 6000, 6000, 6000, Xt, 6016,
                                                            X1a + 7 * 32, X1a + 10 * 32, 352, 2.f, 768);

  // ---- cheb L2 on [c0, c3] ----
  pack_panels<<<63, 256, 0, stream>>>(Xt, 4000, X2a + 0 * 32, X2a + 3 * 32, 192, nullptr, 4000);
  mm_mfma<64, true, false><<<dim3(63, 12), 256, 0, stream>>>(L2, 4000, 4000, 4000, Xt, 4000,
                                                             X2a + 1 * 32, X2a + 4 * 32, 192, 1.f, 352);
  pack_panels<<<63, 256, 0, stream>>>(Xt, 4000, X2a + 1 * 32, X2a + 4 * 32, 192, nullptr, 4000);
  seed_neg2<<<nb(4000 * 32), 256, 0, stream>>>(X2a + 2 * 32, X2a + 0 * 32, X2a + 5 * 32, X2a + 3 * 32, 192, 4000);
  mm_mfma<64, true, false><<<dim3(63, 12), 256, 0, stream>>>(L2, 4000, 4000, 4000, Xt, 4000,
                                                             X2a + 2 * 32, X2a + 5 * 32, 192, 2.f, 352);

  // ---- combine: y = relu(Xall @ Wr), direct store to d_out ----
  pack_w<<<nb(32 * 192), 256, 0, stream>>>(Xt, W0, 6);
  mm_mfma<32, false, true><<<dim3(24, 1), 256, 0, stream>>>(X0a, 192, 1500, 192, Xt, 192,
                                                            out, nullptr, 32, 1.f, 192);
  pack_w<<<nb(32 * 352), 256, 0, stream>>>(Xt, W1, 11);
  mm_mfma<32, false, true><<<dim3(94, 1), 256, 0, stream>>>(X1a, 352, 6000, 352, Xt, 352,
                                                            out + 48000, nullptr, 32, 1.f, 352);
  pack_w<<<nb(32 * 192), 256, 0, stream>>>(Xt, W2, 6);
  mm_mfma<32, false, true><<<dim3(63, 1), 256, 0, stream>>>(X2a, 192, 4000, 192, Xt, 192,
                                                            out + 240000, nullptr, 32, 1.f, 192);
}

// Round 3
// 419.638 us; speedup vs baseline: 1.8090x; 1.0481x over previous
//
#include <hip/hip_runtime.h>
#include <stdint.h>

typedef __attribute__((ext_vector_type(4))) float f32x4;
typedef __attribute__((ext_vector_type(8))) short s16x8;

static __device__ __forceinline__ unsigned short f2bf(float f) {
  union { float f; uint32_t u; } v; v.f = f;
  uint32_t u = v.u;
  u += 0x7fffu + ((u >> 16) & 1u);   // round-to-nearest-even bf16
  return (unsigned short)(u >> 16);
}

// ---------------- fused prep: zero+identity channels for X arrays, diag extraction ----------------
__global__ __launch_bounds__(256) void prep_all(
    const float* __restrict__ x0, const float* __restrict__ x1, const float* __restrict__ x2,
    const float* __restrict__ D1, const float* __restrict__ D2,
    const float* __restrict__ D3, const float* __restrict__ D5,
    float* __restrict__ X0a, float* __restrict__ X1a, float* __restrict__ X2a,
    float* __restrict__ d1i, float* __restrict__ d2v,
    float* __restrict__ d3v, float* __restrict__ d5p) {
  const long NX0 = 1500L * 192, NX1 = 6000L * 384, NX2 = 4000L * 192;
  long idx = (long)blockIdx.x * 256 + threadIdx.x;
  if (idx < NX0) {
    int r = (int)(idx / 192), c = (int)(idx - (long)r * 192);
    X0a[idx] = (c < 32) ? x0[r * 32 + c] : 0.f;
    return;
  }
  idx -= NX0;
  if (idx < NX1) {
    int r = (int)(idx / 384), c = (int)(idx - (long)r * 384);
    X1a[idx] = (c >= 96 && c < 128) ? x1[r * 32 + (c - 96)] : 0.f;
    return;
  }
  idx -= NX1;
  if (idx < NX2) {
    int r = (int)(idx / 192), c = (int)(idx - (long)r * 192);
    X2a[idx] = (c >= 96 && c < 128) ? x2[r * 32 + (c - 96)] : 0.f;
    return;
  }
  idx -= NX2;
  if (idx < 1500) { d1i[idx] = 1.f / D1[idx * 1501]; return; }
  idx -= 1500;
  if (idx < 6000) { d2v[idx] = D2[idx * 6001]; return; }
  idx -= 6000;
  if (idx < 4000) { d3v[idx] = D3[idx * 4001]; return; }
  idx -= 4000;
  if (idx < 6000) { float v = D5[idx * 6001]; d5p[idx] = (v != 0.f) ? 1.f / v : 0.f; }
}

__global__ void copy_chan(float* __restrict__ dst, int ldd,
                          const float* __restrict__ src,
                          const float* __restrict__ svec, int n) {
  int idx = blockIdx.x * blockDim.x + threadIdx.x;
  if (idx >= n * 32) return;
  int r = idx >> 5, f = idx & 31;
  float v = src[idx];
  if (svec) v *= svec[r];
  dst[(size_t)r * ldd + f] = v;
}

__global__ void scale_rows(float* __restrict__ dst, int ldd,
                           const float* __restrict__ svec, int n) {
  int idx = blockIdx.x * blockDim.x + threadIdx.x;
  if (idx >= n * 32) return;
  int r = idx >> 5, f = idx & 31;
  dst[(size_t)r * ldd + f] *= svec[r];
}

__global__ void seed_neg2(float* __restrict__ dA, const float* __restrict__ sA_,
                          float* __restrict__ dB, const float* __restrict__ sB_,
                          int ld, int n) {
  int idx = blockIdx.x * blockDim.x + threadIdx.x;
  if (idx >= n * 32) return;
  int r = idx >> 5, f = idx & 31;
  size_t o = (size_t)r * ld + f;
  dA[o] = -sA_[o];
  dB[o] = -sB_[o];
}

// ---------------- row-major f32 -> bf16 convert with zero col-padding ----------------
__global__ __launch_bounds__(256) void conv_bf16(
    const float* __restrict__ in, int ldi, int n_rows, int n_cols,
    unsigned short* __restrict__ outp, int ldo) {
  int wpr = ldo >> 3;
  long idx = (long)blockIdx.x * 256 + threadIdx.x;
  if (idx >= (long)n_rows * wpr) return;
  int r = (int)(idx / wpr);
  int c = (int)(idx - (long)r * wpr) * 8;
  s16x8 o8 = (s16x8)0;
  const float* ip = in + (size_t)r * ldi + c;
  if (c + 7 < n_cols) {
    f32x4 v0 = *(const f32x4*)ip;
    f32x4 v1 = *(const f32x4*)(ip + 4);
#pragma unroll
    for (int j = 0; j < 4; ++j) { o8[j] = (short)f2bf(v0[j]); o8[4 + j] = (short)f2bf(v1[j]); }
  } else {
#pragma unroll
    for (int j = 0; j < 8; ++j) if (c + j < n_cols) o8[j] = (short)f2bf(ip[j]);
  }
  *(s16x8*)(outp + (size_t)r * ldo + c) = o8;
}

// ---------------- dual-output convert: row-major bf16 + transposed bf16 ----------------
// in: nI x ldi f32 (real cols nC). outR: nI x ldoR bf16 (pad cols zero). outT: nC x ldoT bf16 (pad cols zero).
// grid = (ldoR/64, ldoT/64). outR may be null.
__global__ __launch_bounds__(256) void convT_dual(
    const float* __restrict__ in, int ldi, int nI, int nC,
    unsigned short* __restrict__ outR, int ldoR,
    unsigned short* __restrict__ outT, int ldoT) {
  __shared__ unsigned short sT[64][72];
  const int t = threadIdx.x;
  const int tc0 = blockIdx.x * 64;
  const int tr0 = blockIdx.y * 64;
  const int c0 = (t & 15) * 4;
  const int r0 = (t >> 4) * 4;
  unsigned short ub[4][4];
#pragma unroll
  for (int j = 0; j < 4; ++j) {
    int gr = tr0 + r0 + j;
    f32x4 v = {0.f, 0.f, 0.f, 0.f};
    if (gr < nI) {
      const float* pI = in + (size_t)gr * ldi + tc0 + c0;
      if (tc0 + c0 + 3 < nC) {
        v = *(const f32x4*)pI;
      } else {
#pragma unroll
        for (int jj = 0; jj < 4; ++jj) if (tc0 + c0 + jj < nC) v[jj] = pI[jj];
      }
    }
#pragma unroll
    for (int jj = 0; jj < 4; ++jj) ub[j][jj] = f2bf(v[jj]);
  }
  if (outR) {
#pragma unroll
    for (int j = 0; j < 4; ++j) {
      int gr = tr0 + r0 + j;
      if (gr < nI) {
        union { unsigned short u[4]; unsigned long long ll; } w;
#pragma unroll
        for (int jj = 0; jj < 4; ++jj) w.u[jj] = ub[j][jj];
        *(unsigned long long*)(outR + (size_t)gr * ldoR + tc0 + c0) = w.ll;
      }
    }
  }
#pragma unroll
  for (int jj = 0; jj < 4; ++jj) {
    union { unsigned short u[4]; unsigned long long ll; } w;
#pragma unroll
    for (int j = 0; j < 4; ++j) w.u[j] = ub[j][jj];
    *(unsigned long long*)&sT[c0 + jj][r0] = w.ll;
  }
  __syncthreads();
#pragma unroll
  for (int p = 0; p < 2; ++p) {
    int orow = (t >> 3) + p * 32;
    int rcol = (t & 7) * 8;
    int grow = tc0 + orow;
    int gcol = tr0 + rcol;
    if (grow < nC && gcol < ldoT) {
      union { unsigned long long ll[2]; s16x8 v; } w;
      w.ll[0] = *(const unsigned long long*)&sT[orow][rcol];
      w.ll[1] = *(const unsigned long long*)&sT[orow][rcol + 4];
      *(s16x8*)(outT + (size_t)grow * ldoT + gcol) = w.v;
    }
  }
}

// ---------------- LDS-tiled pack: Xt[64][ldxt] = [src0|src1]^T (bf16), optional row scaling ----------------
__global__ __launch_bounds__(256) void pack_panels(
    unsigned short* __restrict__ Xt, int ldxt,
    const float* __restrict__ src0, const float* __restrict__ src1,
    int lds_, const float* __restrict__ svec, int n) {
  __shared__ unsigned short sT[64][76];
  const int t = threadIdx.x;
  const int tr0 = blockIdx.x * 64;
  const int c0 = (t & 15) * 4;
  const int r0 = (t >> 4) * 4;
  const float* s = (c0 < 32) ? src0 : src1;
  const int cc = c0 & 31;
  float vv[4][4];
#pragma unroll
  for (int j = 0; j < 4; ++j) {
    int gr = tr0 + r0 + j;
    f32x4 v = {0.f, 0.f, 0.f, 0.f};
    if (s && gr < n) {
      v = *(const f32x4*)(s + (size_t)gr * lds_ + cc);
      if (svec) {
        float sc = svec[gr];
#pragma unroll
        for (int jj = 0; jj < 4; ++jj) v[jj] *= sc;
      }
    }
#pragma unroll
    for (int jj = 0; jj < 4; ++jj) vv[j][jj] = v[jj];
  }
#pragma unroll
  for (int jj = 0; jj < 4; ++jj) {
    union { unsigned short u[4]; unsigned long long ll; } w;
#pragma unroll
    for (int j = 0; j < 4; ++j) w.u[j] = f2bf(vv[j][jj]);
    *(unsigned long long*)&sT[c0 + jj][r0] = w.ll;
  }
  __syncthreads();
#pragma unroll
  for (int p = 0; p < 2; ++p) {
    int orow = (t >> 3) + p * 32;
    int rcol = (t & 7) * 8;
    int gcol = tr0 + rcol;
    if (gcol < ldxt) {
      union { unsigned long long ll[2]; s16x8 v; } w;
      w.ll[0] = *(const unsigned long long*)&sT[orow][rcol];
      w.ll[1] = *(const unsigned long long*)&sT[orow][rcol + 4];
      *(s16x8*)(Xt + (size_t)orow * ldxt + gcol) = w.v;
    }
  }
}

// Wr[k*32+i][o] = W[i][o][k] -> Xt[o][k*32+i], zero-padded to Kw_pad
__global__ void pack_w(unsigned short* __restrict__ Xt,
                       const float* __restrict__ W, int K, int Kw_pad) {
  int Kw = K * 32;
  int idx = blockIdx.x * blockDim.x + threadIdx.x;
  if (idx >= 32 * Kw_pad) return;
  int o = idx / Kw_pad;
  int j = idx - o * Kw_pad;
  float v = 0.f;
  if (j < Kw) { int k = j >> 5, i = j & 31; v = W[((size_t)i * 32 + o) * K + k]; }
  Xt[(size_t)o * Kw_pad + j] = f2bf(v);
}

// ---------------- MFMA skinny GEMM, BK=64: C(+)= alpha * A(n_rows x n_k) @ X(n_k x F) ----------------
// A: f32 or bf16 row-major. Xt is X^T, bf16, F x ldxt (16B-safe: ldxt covers all kc..kc+15 reads).
template <int F, bool ATOMIC, bool RELU, typename AT>
__global__ __launch_bounds__(256) void mm_mfma(
    const AT* __restrict__ A, int lda, int n_rows, int n_k,
    const unsigned short* __restrict__ Xt, int ldxt,
    float* __restrict__ C0, float* __restrict__ C1, int ldc,
    float alpha, int kchunk) {
  __shared__ __align__(16) unsigned short sA[64 * 64];
  __shared__ __align__(16) unsigned short sX[64 * 64];

  const int tid = threadIdx.x;
  const int k_begin = blockIdx.y * kchunk;
  const int k_end = min(n_k, k_begin + kchunk);
  if (k_begin >= k_end) return;
  const int nsteps = (k_end - k_begin + 63) >> 6;

  const int srow = tid >> 2;       // 0..63
  const int sslot = tid & 3;       // 16 elems each
  const int kc_off = sslot * 16;
  const long arowg = (long)blockIdx.x * 64 + srow;
  const bool arow_ok = arowg < n_rows;
  const bool xrow_ok = srow < F;

  s16x8 abf0 = (s16x8)0, abf1 = (s16x8)0;
  f32x4 af0, af1, af2, af3;
  s16x8 x0r = (s16x8)0, x1r = (s16x8)0;

  auto load_tiles = [&](int k0) {
    int kc = k0 + kc_off;
    if constexpr (sizeof(AT) == 4) {
      af0 = f32x4{0, 0, 0, 0}; af1 = af0; af2 = af0; af3 = af0;
      if (arow_ok) {
        const float* ap = (const float*)A + (size_t)arowg * lda + kc;
        if (kc + 15 < n_k) {
          af0 = *(const f32x4*)ap; af1 = *(const f32x4*)(ap + 4);
          af2 = *(const f32x4*)(ap + 8); af3 = *(const f32x4*)(ap + 12);
        } else {
#pragma unroll
          for (int j = 0; j < 4; ++j) {
            if (kc + j < n_k) af0[j] = ap[j];
            if (kc + 4 + j < n_k) af1[j] = ap[4 + j];
            if (kc + 8 + j < n_k) af2[j] = ap[8 + j];
            if (kc + 12 + j < n_k) af3[j] = ap[12 + j];
          }
        }
      }
    } else {
      abf0 = (s16x8)0; abf1 = (s16x8)0;
      if (arow_ok) {
        const unsigned short* ap = (const unsigned short*)A + (size_t)arowg * lda + kc;
        if (kc + 15 < n_k) {
          abf0 = *(const s16x8*)ap; abf1 = *(const s16x8*)(ap + 8);
        } else {
#pragma unroll
          for (int j = 0; j < 8; ++j) {
            if (kc + j < n_k) abf0[j] = (short)ap[j];
            if (kc + 8 + j < n_k) abf1[j] = (short)ap[8 + j];
          }
        }
      }
    }
    if (xrow_ok) {
      const unsigned short* xp = Xt + (size_t)srow * ldxt + kc;
      x0r = *(const s16x8*)xp;
      x1r = *(const s16x8*)(xp + 8);
    }
  };

  load_tiles(k_begin);

  const int wave = tid >> 6;
  const int lane = tid & 63;
  const int g = lane >> 4;
  const int r = lane & 15;
  const int wslot0 = ((2 * sslot) ^ (srow & 7)) * 8;
  const int wslot1 = ((2 * sslot + 1) ^ (srow & 7)) * 8;

  f32x4 acc[F / 16];
#pragma unroll
  for (int i = 0; i < F / 16; ++i) acc[i] = f32x4{0.f, 0.f, 0.f, 0.f};

  for (int s = 0; s < nsteps; ++s) {
    s16x8 pk0, pk1;
    if constexpr (sizeof(AT) == 4) {
#pragma unroll
      for (int j = 0; j < 4; ++j) {
        pk0[j] = (short)f2bf(af0[j]); pk0[4 + j] = (short)f2bf(af1[j]);
        pk1[j] = (short)f2bf(af2[j]); pk1[4 + j] = (short)f2bf(af3[j]);
      }
    } else { pk0 = abf0; pk1 = abf1; }
    *(s16x8*)&sA[srow * 64 + wslot0] = pk0;
    *(s16x8*)&sA[srow * 64 + wslot1] = pk1;
    if (xrow_ok) {
      *(s16x8*)&sX[srow * 64 + wslot0] = x0r;
      *(s16x8*)&sX[srow * 64 + wslot1] = x1r;
    }
    __syncthreads();
    if (s + 1 < nsteps) load_tiles(k_begin + (s + 1) * 64);

    const int arow = wave * 16 + r;
#pragma unroll
    for (int kk = 0; kk < 2; ++kk) {
      s16x8 afr = *(s16x8*)&sA[arow * 64 + (((kk * 4 + g) ^ (arow & 7)) << 3)];
#pragma unroll
      for (int nt = 0; nt < F / 16; ++nt) {
        int xc = nt * 16 + r;
        s16x8 bfr = *(s16x8*)&sX[xc * 64 + (((kk * 4 + g) ^ (xc & 7)) << 3)];
        acc[nt] = __builtin_amdgcn_mfma_f32_16x16x32_bf16(afr, bfr, acc[nt], 0, 0, 0);
      }
    }
    __syncthreads();
  }

  // epilogue: C/D layout col = lane&15, row = (lane>>4)*4 + reg
#pragma unroll
  for (int nt = 0; nt < F / 16; ++nt) {
    float* C = (F == 64 && nt >= 2) ? C1 : C0;
    int col = ((F == 64) ? (nt & 1) : nt) * 16 + r;
#pragma unroll
    for (int j = 0; j < 4; ++j) {
      long row = (long)blockIdx.x * 64 + wave * 16 + g * 4 + j;
      if (row < n_rows) {
        float v = alpha * acc[nt][j];
        if (ATOMIC) {
          atomicAdd(&C[(size_t)row * ldc + col], v);
        } else {
          if (RELU) v = fmaxf(v, 0.0f);
          C[(size_t)row * ldc + col] = v;
        }
      }
    }
  }
}

// ---------------- fp32 transposed GEMM (deep fallback only) ----------------
__global__ __launch_bounds__(256) void mm_at(
    const float* __restrict__ A, int lda, int m,
    const float* __restrict__ X,
    float* __restrict__ C, int ldc, int n, int kchunk) {
  const int fg = threadIdx.x & 3;
  const int cg = threadIdx.x >> 2;
  const int c = blockIdx.x * 256 + cg * 4;
  const int k0 = blockIdx.y * kchunk;
  const int k1 = min(m, k0 + kchunk);
  const int f = fg * 8;
  float acc[4][8];
#pragma unroll
  for (int a = 0; a < 4; ++a)
#pragma unroll
    for (int b = 0; b < 8; ++b) acc[a][b] = 0.f;
  for (int k = k0; k < k1; ++k) {
    const float* Ar = A + (size_t)k * lda + c;
    f32x4 a;
    if (c + 3 < n) a = *(const f32x4*)Ar;
    else {
      a = f32x4{0.f, 0.f, 0.f, 0.f};
#pragma unroll
      for (int j = 0; j < 4; ++j) if (c + j < n) a[j] = Ar[j];
    }
    f32x4 xa = *(const f32x4*)(X + (size_t)k * 32 + f);
    f32x4 xb = *(const f32x4*)(X + (size_t)k * 32 + f + 4);
#pragma unroll
    for (int cc = 0; cc < 4; ++cc)
#pragma unroll
      for (int jj = 0; jj < 4; ++jj) {
        acc[cc][jj] += a[cc] * xa[jj];
        acc[cc][4 + jj] += a[cc] * xb[jj];
      }
  }
  if (c >= n) return;
#pragma unroll
  for (int cc = 0; cc < 4; ++cc) {
    if (c + cc >= n) break;
#pragma unroll
    for (int jj = 0; jj < 8; ++jj)
      atomicAdd(&C[(size_t)(c + cc) * ldc + f + jj], acc[cc][jj]);
  }
}

// ---------------- host ----------------

extern "C" void kernel_launch(void* const* d_in, const int* in_sizes, int n_in,
                              void* d_out, int out_size, void* d_ws, size_t ws_size,
                              hipStream_t stream) {
  (void)in_sizes; (void)n_in; (void)out_size;
  const float* x0  = (const float*)d_in[0];
  const float* x1  = (const float*)d_in[1];
  const float* x2  = (const float*)d_in[2];
  const float* B1  = (const float*)d_in[3];
  const float* B2  = (const float*)d_in[4];
  const float* L0  = (const float*)d_in[5];
  const float* L1l = (const float*)d_in[6];
  const float* L1u = (const float*)d_in[7];
  const float* L2  = (const float*)d_in[8];
  const float* D1  = (const float*)d_in[9];
  const float* D2  = (const float*)d_in[10];
  const float* D3  = (const float*)d_in[11];
  const float* D5  = (const float*)d_in[12];
  const float* W0  = (const float*)d_in[13];
  const float* W1  = (const float*)d_in[14];
  const float* W2  = (const float*)d_in[15];
  float* out = (float*)d_out;

  char* p = (char*)d_ws;
  auto alloc = [&](size_t b) { char* r = p; p += (b + 255) & ~(size_t)255; return r; };
  float* d1i = (float*)alloc(1500 * 4);
  float* d2v = (float*)alloc(6000 * 4);
  float* d3v = (float*)alloc(4000 * 4);
  float* d5p = (float*)alloc(6000 * 4);
  float* z0  = (float*)alloc((size_t)1500 * 32 * 4);
  float* sx1 = (float*)alloc((size_t)6000 * 32 * 4);
  float* X0a = (float*)alloc((size_t)1500 * 192 * 4);
  float* X1a = (float*)alloc((size_t)6000 * 384 * 4);
  float* X2a = (float*)alloc((size_t)4000 * 192 * 4);
  unsigned short* Xt = (unsigned short*)alloc((size_t)64 * 6144 * 2);

  size_t usedC = (size_t)(p - (char*)d_ws);
  const size_t sizeT = ((size_t)6000 * 1536 + (size_t)4000 * 6016) * 2 + 1024;
  const size_t sizeL = ((size_t)1500 * 6016 + (size_t)6000 * 4032 + (size_t)1500 * 1536 +
                        2 * (size_t)6000 * 6016 + (size_t)4000 * 4032) * 2 + 4096;
  bool haveT = usedC + sizeT <= ws_size;
  unsigned short *B1t = nullptr, *B2t = nullptr;
  if (haveT) {
    B1t = (unsigned short*)alloc((size_t)6000 * 1536 * 2);
    B2t = (unsigned short*)alloc((size_t)4000 * 6016 * 2);
  }
  bool haveL = haveT && ((size_t)(p - (char*)d_ws) + sizeL <= ws_size);
  unsigned short *B1bf = nullptr, *B2bf = nullptr, *L0bf = nullptr,
                 *L1lbf = nullptr, *L1ubf = nullptr, *L2bf = nullptr;
  if (haveL) {
    B1bf  = (unsigned short*)alloc((size_t)1500 * 6016 * 2);
    B2bf  = (unsigned short*)alloc((size_t)6000 * 4032 * 2);
    L0bf  = (unsigned short*)alloc((size_t)1500 * 1536 * 2);
    L1lbf = (unsigned short*)alloc((size_t)6000 * 6016 * 2);
    L1ubf = (unsigned short*)alloc((size_t)6000 * 6016 * 2);
    L2bf  = (unsigned short*)alloc((size_t)4000 * 4032 * 2);
  }

  auto nb = [](long total) { return (unsigned)((total + 255) / 256); };

  // prep: X arrays (zeros + identity channels) + diag vectors
  prep_all<<<nb(1500L * 192 + 6000L * 384 + 4000L * 192 + 17500), 256, 0, stream>>>(
      x0, x1, x2, D1, D2, D3, D5, X0a, X1a, X2a, d1i, d2v, d3v, d5p);

  // ---- B1 conversions + its two GEMMs ----
  if (haveT) convT_dual<<<dim3(94, 24), 256, 0, stream>>>(B1, 6000, 1500, 6000,
                                                          haveL ? B1bf : nullptr, 6016, B1t, 1536);
  // x0p = d1i * (B1 @ x1) -> X0 ch3
  pack_panels<<<94, 256, 0, stream>>>(Xt, 6016, x1, nullptr, 32, nullptr, 6000);
  if (haveL)
    mm_mfma<32, true, false, unsigned short><<<dim3(24, 24), 256, 0, stream>>>(
        B1bf, 6016, 1500, 6016, Xt, 6016, X0a + 3 * 32, nullptr, 192, 1.f, 256);
  else
    mm_mfma<32, true, false, float><<<dim3(24, 24), 256, 0, stream>>>(
        B1, 6000, 1500, 6000, Xt, 6016, X0a + 3 * 32, nullptr, 192, 1.f, 256);
  scale_rows<<<nb(1500 * 32), 256, 0, stream>>>(X0a + 3 * 32, 192, d1i, 1500);

  // x1n = d2 * (B1^T @ (d1i*x0)) -> X1 ch0
  if (haveT) {
    pack_panels<<<24, 256, 0, stream>>>(Xt, 1536, x0, nullptr, 32, d1i, 1500);
    mm_mfma<32, true, false, unsigned short><<<dim3(94, 6), 256, 0, stream>>>(
        B1t, 1536, 6000, 1536, Xt, 1536, X1a + 0 * 32, nullptr, 384, 1.f, 256);
  } else {
    copy_chan<<<nb(1500 * 32), 256, 0, stream>>>(z0, 32, x0, d1i, 1500);
    mm_at<<<dim3(24, 24), 256, 0, stream>>>(B1, 6000, 1500, z0, X1a + 0 * 32, 384, 6000, 63);
  }
  scale_rows<<<nb(6000 * 32), 256, 0, stream>>>(X1a + 0 * 32, 384, d2v, 6000);

  // ---- B2 conversions + its two GEMMs ----
  if (haveT) convT_dual<<<dim3(63, 94), 256, 0, stream>>>(B2, 4000, 6000, 4000,
                                                          haveL ? B2bf : nullptr, 4032, B2t, 6016);
  // x1p = B2 @ (d3 * x2) -> X1 ch8
  pack_panels<<<63, 256, 0, stream>>>(Xt, 4032, x2, nullptr, 32, d3v, 4000);
  if (haveL)
    mm_mfma<32, true, false, unsigned short><<<dim3(94, 7), 256, 0, stream>>>(
        B2bf, 4032, 6000, 4032, Xt, 4032, X1a + 8 * 32, nullptr, 384, 1.f, 576);
  else
    mm_mfma<32, true, false, float><<<dim3(94, 7), 256, 0, stream>>>(
        B2, 4000, 6000, 4000, Xt, 4032, X1a + 8 * 32, nullptr, 384, 1.f, 576);

  // x2n = B2^T @ (d5p * x1) -> X2 ch0
  if (haveT) {
    pack_panels<<<94, 256, 0, stream>>>(Xt, 6016, x1, nullptr, 32, d5p, 6000);
    mm_mfma<32, true, false, unsigned short><<<dim3(63, 8), 256, 0, stream>>>(
        B2t, 6016, 4000, 6016, Xt, 6016, X2a + 0 * 32, nullptr, 192, 1.f, 768);
  } else {
    copy_chan<<<nb(6000 * 32), 256, 0, stream>>>(sx1, 32, x1, d5p, 6000);
    mm_at<<<dim3(16, 32), 256, 0, stream>>>(B2, 4000, 6000, sx1, X2a + 0 * 32, 192, 4000, 188);
  }

  // ---- Chebyshev groups: T1 = L@[a|b]; T2 = 2*L@T1 - [a|b] ----
  auto cheb = [&](const unsigned short* Lbf, const float* Lf, int n, int ldbf,
                  int rowTiles, int ky, int kchunk, int ldxt,
                  float* Xb, int ldX, int sA_, int sB_, int t1A, int t1B, int t2A, int t2B) {
    int packTiles = ldxt / 64;
    pack_panels<<<packTiles, 256, 0, stream>>>(Xt, ldxt, Xb + sA_ * 32, Xb + sB_ * 32, ldX, nullptr, n);
    if (Lbf)
      mm_mfma<64, true, false, unsigned short><<<dim3(rowTiles, ky), 256, 0, stream>>>(
          Lbf, ldbf, n, ldbf, Xt, ldxt, Xb + t1A * 32, Xb + t1B * 32, ldX, 1.f, kchunk);
    else
      mm_mfma<64, true, false, float><<<dim3(rowTiles, ky), 256, 0, stream>>>(
          Lf, n, n, n, Xt, ldxt, Xb + t1A * 32, Xb + t1B * 32, ldX, 1.f, kchunk);
    pack_panels<<<packTiles, 256, 0, stream>>>(Xt, ldxt, Xb + t1A * 32, Xb + t1B * 32, ldX, nullptr, n);
    seed_neg2<<<nb((long)n * 32), 256, 0, stream>>>(Xb + t2A * 32, Xb + sA_ * 32,
                                                    Xb + t2B * 32, Xb + sB_ * 32, ldX, n);
    if (Lbf)
      mm_mfma<64, true, false, unsigned short><<<dim3(rowTiles, ky), 256, 0, stream>>>(
          Lbf, ldbf, n, ldbf, Xt, ldxt, Xb + t2A * 32, Xb + t2B * 32, ldX, 2.f, kchunk);
    else
      mm_mfma<64, true, false, float><<<dim3(rowTiles, ky), 256, 0, stream>>>(
          Lf, n, n, n, Xt, ldxt, Xb + t2A * 32, Xb + t2B * 32, ldX, 2.f, kchunk);
  };

  if (haveL) conv_bf16<<<nb(1500L * 192), 256, 0, stream>>>(L0, 1500, 1500, 1500, L0bf, 1536);
  cheb(haveL ? L0bf : nullptr, L0, 1500, 1536, 24, 12, 128, 1536, X0a, 192, 0, 3, 1, 4, 2, 5);

  if (haveL) conv_bf16<<<nb(6000L * 752), 256, 0, stream>>>(L1l, 6000, 6000, 6000, L1lbf, 6016);
  cheb(haveL ? L1lbf : nullptr, L1l, 6000, 6016, 94, 8, 768, 6016, X1a, 384, 0, 3, 1, 4, 2, 5);

  if (haveL) conv_bf16<<<nb(6000L * 752), 256, 0, stream>>>(L1u, 6000, 6000, 6000, L1ubf, 6016);
  cheb(haveL ? L1ubf : nullptr, L1u, 6000, 6016, 94, 8, 768, 6016, X1a, 384, 3, 8, 6, 9, 7, 10);

  if (haveL) conv_bf16<<<nb(4000L * 504), 256, 0, stream>>>(L2, 4000, 4000, 4000, L2bf, 4032);
  cheb(haveL ? L2bf : nullptr, L2, 4000, 4032, 63, 7, 576, 4032, X2a, 192, 0, 3, 1, 4, 2, 5);

  // ---- finals: y = relu(X @ W), direct to d_out ----
  pack_w<<<nb(32 * 192), 256, 0, stream>>>(Xt, W0, 6, 192);
  mm_mfma<32, false, true, float><<<dim3(24, 1), 256, 0, stream>>>(
      X0a, 192, 1500, 192, Xt, 192, out, nullptr, 32, 1.f, 192);
  pack_w<<<nb(32 * 384), 256, 0, stream>>>(Xt, W1, 11, 384);
  mm_mfma<32, false, true, float><<<dim3(94, 1), 256, 0, stream>>>(
      X1a, 384, 6000, 384, Xt, 384, out + 48000, nullptr, 32, 1.f, 384);
  pack_w<<<nb(32 * 192), 256, 0, stream>>>(Xt, W2, 6, 192);
  mm_mfma<32, false, true, float><<<dim3(63, 1), 256, 0, stream>>>(
      X2a, 192, 4000, 192, Xt, 192, out + 240000, nullptr, 32, 1.f, 192);
}